// Round 7
// baseline (845.333 us; speedup 1.0000x reference)
//
#include <hip/hip_runtime.h>
#include <math.h>

#define HW    36864
#define IMG   192

// ---- ws layout (float offsets) ----
#define OFF_RS_QKV   0          // 384
#define OFF_B_QKV    384        // 384
#define OFF_RS_FFN   768        // 256
#define OFF_B_FFN    1024       // 256
#define OFF_SSQ      1280       // 1024 [zeroed]
#define OFF_AVG      2304       // 512  [zeroed]
#define OFF_MAXK     2816       // 512  [zeroed]
#define OFF_A        3328       // 32768 softmax probs
#define OFF_MU1      36096      // 147456
#define OFF_RSTD1    183552     // 147456
#define OFF_MU2      331008     // 147456
#define OFF_RSTD2    478464     // 147456
#define OFF_PART     625920     // 8*64*4096 = 2097152
#define OFF_AQH      2723072    // 384x128 bf16 hi
#define OFF_AQL      2747648
#define OFF_AFH      2772224    // 256x128
#define OFF_AFL      2788608
#define OFF_AOH      2804992    // 128x256
#define OFF_AOL      2821376
// Each bf16 buffer: 4 batches x 384 ch x HW = 56,623,104 ushorts = 28,311,552 floats
#define OFF_BUFA     2837760    // ends 31,149,312
#define OFF_BUFB     31149312   // ends 59,460,864 floats (237.8 MB)

typedef __attribute__((ext_vector_type(8))) short short8v;
typedef __attribute__((ext_vector_type(4))) unsigned short ushort4v;
typedef __attribute__((ext_vector_type(4))) float floatx4;

__device__ __forceinline__ unsigned f2key(float f){
  unsigned b = __float_as_uint(f);
  return (b & 0x80000000u) ? ~b : (b | 0x80000000u);
}
__device__ __forceinline__ float key2f(unsigned k){
  return __uint_as_float((k & 0x80000000u) ? (k & 0x7fffffffu) : ~k);
}
__device__ __forceinline__ float gelu_f(float v){
  return 0.5f*v*(1.0f + erff(v*0.70710678118654752f));
}
__device__ __forceinline__ unsigned short bf16rn(float v){
  unsigned u = __float_as_uint(v);
  return (unsigned short)((u + 0x7FFFu + ((u>>16)&1u)) >> 16);
}
__device__ __forceinline__ float bf2f(unsigned short h){
  return __uint_as_float(((unsigned)h)<<16);
}
// LDS swizzle: row pitch 64 ushorts; k8 = 8-elem k-group index 0..7
__device__ __forceinline__ int bofs(int p, int k8){
  return (p<<6) + ((k8 ^ (p&7) ^ ((p>>3)&7))<<3);
}

__global__ __launch_bounds__(256) void k_init(float* ws){
  int t = blockIdx.x*256 + threadIdx.x;
  if (t < 2048) ws[OFF_SSQ + t] = 0.0f;
}

// LN fold constants + split-bf16 weight tables
__global__ void k_prep(const float* wq, const float* wk, const float* wv,
                       const float* f1, const float* f2, const float* fo,
                       const float* liw, const float* lib,
                       const float* low, const float* lob, float* ws){
  int t = blockIdx.x*256 + threadIdx.x;
  if (t < 384){
    const float* W = (t < 128) ? wq : (t < 256) ? wk : wv;
    int r = t & 127;
    float rs = 0.f, bs = 0.f;
    for (int c = 0; c < 128; c++){ float w = W[r*128+c]; rs += w*liw[c]; bs += w*lib[c]; }
    ws[OFF_RS_QKV+t] = rs; ws[OFF_B_QKV+t] = bs;
  } else if (t < 640){
    int m = t - 384;
    const float* W = (m < 128) ? f1 : f2;
    int r = m & 127;
    float rs = 0.f, bs = 0.f;
    for (int c = 0; c < 128; c++){ float w = W[r*128+c]; rs += w*low[c]; bs += w*lob[c]; }
    ws[OFF_RS_FFN+m] = rs; ws[OFF_B_FFN+m] = bs;
  }
  int e = t - 640;
  if (e < 0) return;
  unsigned short* aqh = (unsigned short*)(ws + OFF_AQH);
  unsigned short* aql = (unsigned short*)(ws + OFF_AQL);
  unsigned short* afh = (unsigned short*)(ws + OFF_AFH);
  unsigned short* afl = (unsigned short*)(ws + OFF_AFL);
  unsigned short* aoh = (unsigned short*)(ws + OFF_AOH);
  unsigned short* aol = (unsigned short*)(ws + OFF_AOL);
  if (e < 49152){
    int m = e>>7, k = e&127;
    const float* W = (m < 128) ? wq : (m < 256) ? wk : wv;
    float v = W[(m&127)*128 + k]*liw[k];
    unsigned short h = bf16rn(v);
    aqh[e] = h; aql[e] = bf16rn(v - bf2f(h));
  } else if (e < 81920){
    int e2 = e - 49152;
    int m = e2>>7, k = e2&127;
    const float* W = (m < 128) ? f1 : f2;
    float v = W[(m&127)*128 + k]*low[k];
    unsigned short h = bf16rn(v);
    afh[e2] = h; afl[e2] = bf16rn(v - bf2f(h));
  } else if (e < 114688){
    int e2 = e - 81920;
    float v = fo[e2];
    unsigned short h = bf16rn(v);
    aoh[e2] = h; aol[e2] = bf16rn(v - bf2f(h));
  }
}

__global__ __launch_bounds__(256) void k_stats(const float* __restrict__ x, float* __restrict__ ws){
  int t = threadIdx.x, b = blockIdx.y;
  int p0 = blockIdx.x*1024 + t*4;
  const float* xp = x + (size_t)b*128*HW + p0;
  float s[4] = {}, q[4] = {};
  #pragma unroll 4
  for (int c = 0; c < 128; c++){
    float4 v = *(const float4*)(xp + (size_t)c*HW);
    float vv[4] = {v.x,v.y,v.z,v.w};
    #pragma unroll
    for (int j = 0; j < 4; j++){ s[j] += vv[j]; q[j] += vv[j]*vv[j]; }
  }
  float mu[4], rs[4];
  #pragma unroll
  for (int j = 0; j < 4; j++){
    mu[j] = s[j]*(1.f/128.f);
    rs[j] = rsqrtf(q[j]*(1.f/128.f) - mu[j]*mu[j] + 1e-5f);
  }
  size_t g = (size_t)b*HW + p0;
  *(float4*)&ws[OFF_MU1 + g]   = make_float4(mu[0],mu[1],mu[2],mu[3]);
  *(float4*)&ws[OFF_RSTD1 + g] = make_float4(rs[0],rs[1],rs[2],rs[3]);
}

// MFMA GEMM: A = bf16 hi/lo weight table (LN folded), B = src (fp32 or bf16),
// single-bf16 B in LDS, 2 MFMA passes. Epilogue: LN fold (+GELU), bf16 store.
template<bool GELU, bool SRCBF16>
__global__ __launch_bounds__(512,8) void k_gemm_mfma(
    const void* __restrict__ srcv, int src_bstride,
    const unsigned short* __restrict__ Ahi, const unsigned short* __restrict__ Alo,
    const float* __restrict__ rowsum, const float* __restrict__ bias,
    const float* __restrict__ mu, const float* __restrict__ rstd,
    unsigned short* __restrict__ dst, int dst_coff)
{
  __shared__ unsigned short Bs[2][8192];
  int t = threadIdx.x;
  int m0 = blockIdx.x*128, p0 = blockIdx.y*128, b = blockIdx.z;
  int px0 = (t&63)<<1, kb0 = t>>6;
  int lane = t&63, wv = t>>6;
  int wm = (wv&3)*32, wn = (wv>>2)*64;
  int colg = lane&15, kg = lane>>4;
  float2 rv[8];
  unsigned rv16[8];
  const float* sbase32 = SRCBF16 ? (const float*)nullptr
      : ((const float*)srcv + ((size_t)b*src_bstride)*HW + p0 + px0);
  const unsigned short* sbase16 = SRCBF16
      ? ((const unsigned short*)srcv + ((size_t)b*src_bstride)*HW + p0 + px0)
      : (const unsigned short*)nullptr;

  auto loadreg = [&](int h){
    if (SRCBF16){
      const unsigned short* sp = sbase16 + ((size_t)(h*64 + kb0*8))*HW;
      #pragma unroll
      for (int e = 0; e < 8; e++) rv16[e] = *(const unsigned*)(sp + (size_t)e*HW);
    } else {
      const float* sp = sbase32 + ((size_t)(h*64 + kb0*8))*HW;
      #pragma unroll
      for (int e = 0; e < 8; e++) rv[e] = *(const float2*)(sp + (size_t)e*HW);
    }
  };
  auto convstore = [&](int bi){
    #pragma unroll
    for (int j = 0; j < 2; j++){
      int p = px0 + j;
      short8v hv;
      #pragma unroll
      for (int e = 0; e < 8; e++){
        if (SRCBF16) hv[e] = (short)(unsigned short)((j==0) ? (rv16[e]&0xFFFFu) : (rv16[e]>>16));
        else         hv[e] = (short)bf16rn((j==0)?rv[e].x:rv[e].y);
      }
      *(short8v*)&Bs[bi][bofs(p, kb0)] = hv;
    }
  };

  floatx4 acc[2][4];
  #pragma unroll
  for (int i = 0; i < 2; i++)
    #pragma unroll
    for (int j = 0; j < 4; j++) acc[i][j] = (floatx4){0.f,0.f,0.f,0.f};

  auto mfmah = [&](int bi, int h){
    #pragma unroll
    for (int kt = 0; kt < 2; kt++){
      int kb = kt*32 + kg*8;
      short8v ah[2], al[2], bh[4];
      #pragma unroll
      for (int f = 0; f < 2; f++){
        size_t arow = (size_t)(m0 + wm + f*16 + colg)*128 + h*64 + kb;
        ah[f] = *(const short8v*)(Ahi + arow);
        al[f] = *(const short8v*)(Alo + arow);
      }
      #pragma unroll
      for (int f = 0; f < 4; f++)
        bh[f] = *(const short8v*)&Bs[bi][bofs(wn + f*16 + colg, kb>>3)];
      #pragma unroll
      for (int i = 0; i < 2; i++)
        #pragma unroll
        for (int j = 0; j < 4; j++){
          acc[i][j] = __builtin_amdgcn_mfma_f32_16x16x32_bf16(al[i], bh[j], acc[i][j], 0,0,0);
          acc[i][j] = __builtin_amdgcn_mfma_f32_16x16x32_bf16(ah[i], bh[j], acc[i][j], 0,0,0);
        }
    }
  };

  loadreg(0); convstore(0);
  __syncthreads();
  loadreg(1);
  mfmah(0, 0);
  convstore(1);
  __syncthreads();
  mfmah(1, 1);

  int rowg = kg*4;
  const float* mub = mu   + (size_t)b*HW + p0;
  const float* rsb = rstd + (size_t)b*HW + p0;
  #pragma unroll
  for (int j = 0; j < 4; j++){
    int pc = wn + j*16 + colg;
    float muv = mub[pc], rsv = rsb[pc];
    #pragma unroll
    for (int i = 0; i < 2; i++){
      int mbase = m0 + wm + i*16 + rowg;
      float4 rs4 = *(const float4*)&rowsum[mbase];
      float4 bi4 = *(const float4*)&bias[mbase];
      float rsa[4] = {rs4.x,rs4.y,rs4.z,rs4.w};
      float bia[4] = {bi4.x,bi4.y,bi4.z,bi4.w};
      #pragma unroll
      for (int e = 0; e < 4; e++){
        float v = rsv*(acc[i][j][e] - muv*rsa[e]) + bia[e];
        if (GELU) v = gelu_f(v);
        dst[((size_t)(b*384 + dst_coff + mbase + e))*HW + p0 + pc] = bf16rn(v);
      }
    }
  }
}

// depthwise 3x3 (pad 1), bf16 in/out, px-pair processing.
// SSQ accumulates from the ROUNDED outputs (consistent with downstream gram).
template<bool GELU, bool SSQ>
__global__ __launch_bounds__(256) void k_dw(const unsigned short* __restrict__ src,
                                            const float* __restrict__ wdw,
                                            unsigned short* __restrict__ dst,
                                            float* __restrict__ ssq, int ssq_off){
  __shared__ float rows[10][194];
  __shared__ float wred[4];
  int t = threadIdx.x;
  int band = blockIdx.x, c = blockIdx.y, b = blockIdx.z;
  const unsigned short* sp = src + ((size_t)(b*384 + c))*HW;
  float w[9];
  #pragma unroll
  for (int j = 0; j < 9; j++) w[j] = wdw[c*9 + j];
  int r0 = band*8;
  for (int e = t; e < 960; e += 256){
    int r = e/96, c2 = e - r*96;
    int gr = r0 + r - 1;
    unsigned pv = (gr >= 0 && gr < IMG) ? *(const unsigned*)(sp + gr*IMG + c2*2) : 0u;
    rows[r][c2*2+1] = bf2f((unsigned short)(pv & 0xFFFFu));
    rows[r][c2*2+2] = bf2f((unsigned short)(pv >> 16));
  }
  if (t < 20) rows[t>>1][(t&1)*193] = 0.f;
  __syncthreads();
  float s2 = 0.f;
  unsigned short* dp = dst + ((size_t)(b*384 + c))*HW + r0*IMG;
  #pragma unroll
  for (int i = 0; i < 3; i++){
    int pi = i*256 + t;           // 768 px-pairs
    int r = pi/96, cp = pi - r*96;
    float v0 = 0.f, v1 = 0.f;
    #pragma unroll
    for (int dy = 0; dy < 3; dy++)
      #pragma unroll
      for (int dx = 0; dx < 3; dx++){
        float wv = w[dy*3+dx];
        v0 += rows[r+dy][cp*2+dx]   * wv;
        v1 += rows[r+dy][cp*2+1+dx] * wv;
      }
    if (GELU){ v0 = gelu_f(v0); v1 = gelu_f(v1); }
    unsigned short u0 = bf16rn(v0), u1 = bf16rn(v1);
    if (SSQ){
      float f0 = bf2f(u0), f1 = bf2f(u1);
      s2 += f0*f0 + f1*f1;
    }
    *(unsigned*)(dp + r*IMG + cp*2) = (unsigned)u0 | ((unsigned)u1 << 16);
  }
  if (SSQ){
    #pragma unroll
    for (int off = 32; off; off >>= 1) s2 += __shfl_xor(s2, off);
    if ((t & 63) == 0) wred[t>>6] = s2;
    __syncthreads();
    if (t == 0) atomicAdd(&ssq[b*256 + ssq_off + c], wred[0]+wred[1]+wred[2]+wred[3]);
  }
}

// split-K 64x64 gram over bf16 q2,k2
__global__ __launch_bounds__(256,4) void k_qk(const unsigned short* __restrict__ buf,
                                              float* __restrict__ part){
  __shared__ float qs[64][68];
  __shared__ float ks[64][68];
  int t = threadIdx.x;
  int chunk = blockIdx.x, h = blockIdx.y, b = blockIdx.z;
  int tc = (t>>4)<<2, td = (t&15)<<2;
  int c = t>>2, pq = (t&3)<<4;
  const unsigned short* qp = buf + ((size_t)(b*384 +       h*64 + c))*HW + chunk*576 + pq;
  const unsigned short* kp = buf + ((size_t)(b*384 + 128 + h*64 + c))*HW + chunk*576 + pq;
  float acc[4][4] = {};
  for (int st = 0; st < 9; st++){
    __syncthreads();
    short8v q0 = *(const short8v*)(qp + st*64);
    short8v q1 = *(const short8v*)(qp + st*64 + 8);
    short8v k0 = *(const short8v*)(kp + st*64);
    short8v k1 = *(const short8v*)(kp + st*64 + 8);
    #pragma unroll
    for (int u = 0; u < 8; u++){
      qs[pq+u][c]   = bf2f((unsigned short)q0[u]);
      qs[pq+8+u][c] = bf2f((unsigned short)q1[u]);
      ks[pq+u][c]   = bf2f((unsigned short)k0[u]);
      ks[pq+8+u][c] = bf2f((unsigned short)k1[u]);
    }
    __syncthreads();
    #pragma unroll 4
    for (int p = 0; p < 64; p++){
      float4 q4 = *(const float4*)&qs[p][tc];
      float4 k4 = *(const float4*)&ks[p][td];
      float qa[4] = {q4.x,q4.y,q4.z,q4.w};
      float ka[4] = {k4.x,k4.y,k4.z,k4.w};
      #pragma unroll
      for (int i = 0; i < 4; i++)
        #pragma unroll
        for (int j = 0; j < 4; j++) acc[i][j] += qa[i]*ka[j];
    }
  }
  float* pp = part + ((size_t)((b*2+h)*64 + chunk))*4096;
  #pragma unroll
  for (int i = 0; i < 4; i++)
    *(float4*)&pp[(tc+i)*64 + td] = make_float4(acc[i][0],acc[i][1],acc[i][2],acc[i][3]);
}

__global__ __launch_bounds__(256) void k_softmax(const float* __restrict__ part,
                                                 const float* __restrict__ ssq,
                                                 const float* __restrict__ scale,
                                                 float* __restrict__ ws_a,
                                                 float* __restrict__ out)
{
  __shared__ float red[8][64];
  __shared__ float rnk[64];
  int t = threadIdx.x;
  int c0 = blockIdx.x*8, h = blockIdx.y, b = blockIdx.z;
  int bh = b*2 + h;
  const float* pp = part + (size_t)bh*64*4096;
  for (int e = t; e < 512; e += 256){
    int c = e>>6, d = e&63;
    float s = 0.f;
    for (int ch = 0; ch < 64; ch++) s += pp[(size_t)ch*4096 + (c0+c)*64 + d];
    red[c][d] = s;
  }
  if (t < 64) rnk[t] = 1.0f/fmaxf(sqrtf(ssq[b*256 + 128 + h*64 + t]), 1e-12f);
  __syncthreads();
  if (t < 8){
    int c = c0 + t;
    float rq = (1.0f/fmaxf(sqrtf(ssq[b*256 + h*64 + c]), 1e-12f))*scale[h];
    float vals[64], vmax = -1e30f;
    for (int d = 0; d < 64; d++){
      float v = red[t][d]*rq*rnk[d];
      vals[d] = v; vmax = fmaxf(vmax, v);
    }
    float* aw = out + 512 + ((size_t)(b*128 + h*64 + c))*64;
    for (int d = 0; d < 64; d++) aw[d] = vals[d];
    float se = 0.f;
    for (int d = 0; d < 64; d++){ float e = expf(vals[d]-vmax); vals[d] = e; se += e; }
    float inv = 1.0f/se;
    float* ar = ws_a + ((size_t)(b*128 + h*64 + c))*64;
    for (int d = 0; d < 64; d++) ar[d] = vals[d]*inv;
  }
}

// out = a @ v2 (block-diag per head), bf16 v in / bf16 out, LN stats from rounded
__global__ __launch_bounds__(256,2) void k_av(const float* __restrict__ ws_a,
                                              const unsigned short* __restrict__ buf,
                                              unsigned short* __restrict__ dst,
                                              float* __restrict__ mu2,
                                              float* __restrict__ rstd2)
{
  __shared__ float a_t[64][128];
  __shared__ float v_l[128][64];
  int t = threadIdx.x;
  int pt = blockIdx.x, b = blockIdx.y;
  int p0 = pt*64;
  {
    int c = t>>1, dh = (t&1)<<5;
    const float* ap = ws_a + ((size_t)(b*128 + c))*64 + dh;
    #pragma unroll
    for (int u = 0; u < 8; u++){
      float4 v = *(const float4*)(ap + u*4);
      int d = dh + u*4;
      a_t[d+0][c] = v.x; a_t[d+1][c] = v.y; a_t[d+2][c] = v.z; a_t[d+3][c] = v.w;
    }
    const unsigned short* vp = buf + ((size_t)(b*384 + 256 + c))*HW + p0 + dh;
    #pragma unroll
    for (int u = 0; u < 4; u++){
      short8v v8 = *(const short8v*)(vp + u*8);
      #pragma unroll
      for (int z = 0; z < 8; z++) v_l[c][dh + u*8 + z] = bf2f((unsigned short)v8[z]);
    }
  }
  __syncthreads();
  int tm = (t>>4)<<3, tp = (t&15)<<2;
  int hd = tm>>6;
  float acc[8][4] = {};
  #pragma unroll 2
  for (int d = 0; d < 64; d++){
    float4 v4 = *(const float4*)&v_l[hd*64+d][tp];
    float vv[4] = {v4.x,v4.y,v4.z,v4.w};
    #pragma unroll
    for (int i = 0; i < 8; i++){
      float av = a_t[d][tm+i];
      #pragma unroll
      for (int j = 0; j < 4; j++) acc[i][j] += av*vv[j];
    }
  }
  #pragma unroll
  for (int i = 0; i < 8; i++){
    ushort4v u4;
    #pragma unroll
    for (int j = 0; j < 4; j++){
      unsigned short us = bf16rn(acc[i][j]);
      acc[i][j] = bf2f(us);          // stats from rounded value
      u4[j] = us;
    }
    *(ushort4v*)(dst + ((size_t)(b*384 + tm+i))*HW + p0 + tp) = u4;
  }
  __syncthreads();
  float* px = &a_t[0][0];
  if (t < 128) px[t] = 0.f;
  __syncthreads();
  #pragma unroll
  for (int j = 0; j < 4; j++){
    float s = 0.f, q = 0.f;
    #pragma unroll
    for (int i = 0; i < 8; i++){ s += acc[i][j]; q += acc[i][j]*acc[i][j]; }
    atomicAdd(&px[tp+j], s);
    atomicAdd(&px[64+tp+j], q);
  }
  __syncthreads();
  if (t < 64){
    float mu  = px[t]*(1.f/128.f);
    float var = px[64+t]*(1.f/128.f) - mu*mu;
    mu2[(size_t)b*HW + p0 + t]   = mu;
    rstd2[(size_t)b*HW + p0 + t] = rsqrtf(var + 1e-5f);
  }
}

// f_out GEMM (K=256) over bf16 z; A hi/lo; pool-only epilogue
__global__ __launch_bounds__(512,8) void k_fout_mfma(
    const unsigned short* __restrict__ bufz,
    const unsigned short* __restrict__ Ahi, const unsigned short* __restrict__ Alo,
    float* __restrict__ avg, unsigned* __restrict__ maxk)
{
  __shared__ unsigned short Bs[2][8192];
  __shared__ float osum[128];
  __shared__ unsigned okey[128];
  int t = threadIdx.x;
  int p0 = blockIdx.x*128, b = blockIdx.y;
  if (t < 128){ osum[t] = 0.f; okey[t] = 0u; }
  int px0 = (t&63)<<1, kb0 = t>>6;
  int lane = t&63, wv = t>>6;
  int wm = (wv&3)*32, wn = (wv>>2)*64;
  int colg = lane&15, kg = lane>>4;
  unsigned rv16[8];
  const unsigned short* sbase = bufz + ((size_t)b*384)*HW + p0 + px0;

  auto loadreg = [&](int h){
    const unsigned short* sp = sbase + ((size_t)(h*64 + kb0*8))*HW;
    #pragma unroll
    for (int e = 0; e < 8; e++) rv16[e] = *(const unsigned*)(sp + (size_t)e*HW);
  };
  auto convstore = [&](int bi){
    #pragma unroll
    for (int j = 0; j < 2; j++){
      int p = px0 + j;
      short8v hv;
      #pragma unroll
      for (int e = 0; e < 8; e++)
        hv[e] = (short)(unsigned short)((j==0) ? (rv16[e]&0xFFFFu) : (rv16[e]>>16));
      *(short8v*)&Bs[bi][bofs(p, kb0)] = hv;
    }
  };

  floatx4 acc[2][4];
  #pragma unroll
  for (int i = 0; i < 2; i++)
    #pragma unroll
    for (int j = 0; j < 4; j++) acc[i][j] = (floatx4){0.f,0.f,0.f,0.f};

  auto mfmah = [&](int bi, int h){
    #pragma unroll
    for (int kt = 0; kt < 2; kt++){
      int kb = kt*32 + kg*8;
      short8v ah[2], al[2], bh[4];
      #pragma unroll
      for (int f = 0; f < 2; f++){
        size_t arow = (size_t)(wm + f*16 + colg)*256 + h*64 + kb;
        ah[f] = *(const short8v*)(Ahi + arow);
        al[f] = *(const short8v*)(Alo + arow);
      }
      #pragma unroll
      for (int f = 0; f < 4; f++)
        bh[f] = *(const short8v*)&Bs[bi][bofs(wn + f*16 + colg, kb>>3)];
      #pragma unroll
      for (int i = 0; i < 2; i++)
        #pragma unroll
        for (int j = 0; j < 4; j++){
          acc[i][j] = __builtin_amdgcn_mfma_f32_16x16x32_bf16(al[i], bh[j], acc[i][j], 0,0,0);
          acc[i][j] = __builtin_amdgcn_mfma_f32_16x16x32_bf16(ah[i], bh[j], acc[i][j], 0,0,0);
        }
    }
  };

  loadreg(0); convstore(0);
  __syncthreads();
  #pragma unroll
  for (int h = 1; h < 4; h++){
    loadreg(h);
    mfmah((h-1)&1, h-1);
    convstore(h&1);
    __syncthreads();
  }
  mfmah(1, 3);

  int rowg = kg*4;
  #pragma unroll
  for (int i = 0; i < 2; i++){
    #pragma unroll
    for (int e = 0; e < 4; e++){
      float s = 0.f, mx = -1e30f;
      #pragma unroll
      for (int j = 0; j < 4; j++){ float v = acc[i][j][e]; s += v; mx = fmaxf(mx, v); }
      #pragma unroll
      for (int off = 1; off < 16; off <<= 1){
        s += __shfl_xor(s, off);
        mx = fmaxf(mx, __shfl_xor(mx, off));
      }
      if (colg == 0){
        int oc = wm + i*16 + rowg + e;
        atomicAdd(&osum[oc], s);
        atomicMax(&okey[oc], f2key(mx));
      }
    }
  }
  __syncthreads();
  if (t < 128){
    atomicAdd(&avg[b*128+t], osum[t]);
    atomicMax(&maxk[b*128+t], okey[t]);
  }
}

__global__ __launch_bounds__(128) void k_gate(const float* __restrict__ avg,
                                              const unsigned* __restrict__ maxk,
                                              const float* __restrict__ w1, const float* __restrict__ b1,
                                              const float* __restrict__ w2, const float* __restrict__ b2,
                                              float* __restrict__ out)
{
  __shared__ float ap[128], mp[128], h1a[8], h1m[8];
  int t = threadIdx.x, b = blockIdx.x;
  ap[t] = avg[b*128+t]*(1.0f/36864.0f);
  mp[t] = key2f(maxk[b*128+t]);
  __syncthreads();
  if (t < 8){
    float sa = b1[t], sm = b1[t];
    for (int c = 0; c < 128; c++){ float w = w1[t*128+c]; sa += w*ap[c]; sm += w*mp[c]; }
    h1a[t] = fmaxf(sa, 0.f); h1m[t] = fmaxf(sm, 0.f);
  }
  __syncthreads();
  float y = 2.0f*b2[t];
  for (int r = 0; r < 8; r++) y += w2[t*8+r]*(h1a[r]+h1m[r]);
  out[b*128+t] = 1.0f/(1.0f+expf(-y));
}

extern "C" void kernel_launch(void* const* d_in, const int* in_sizes, int n_in,
                              void* d_out, int out_size, void* d_ws, size_t ws_size,
                              hipStream_t stream)
{
  const float* x        = (const float*)d_in[0];
  const float* ln_in_w  = (const float*)d_in[1];
  const float* ln_in_b  = (const float*)d_in[2];
  const float* wq_pw    = (const float*)d_in[3];
  const float* wq_dw    = (const float*)d_in[4];
  const float* wk_pw    = (const float*)d_in[5];
  const float* wk_dw    = (const float*)d_in[6];
  const float* wv_pw    = (const float*)d_in[7];
  const float* wv_dw    = (const float*)d_in[8];
  const float* scale    = (const float*)d_in[9];
  const float* ln_out_w = (const float*)d_in[10];
  const float* ln_out_b = (const float*)d_in[11];
  const float* f1_pw    = (const float*)d_in[12];
  const float* f1_dw    = (const float*)d_in[13];
  const float* f2_pw    = (const float*)d_in[14];
  const float* f2_dw    = (const float*)d_in[15];
  const float* f_out    = (const float*)d_in[16];
  const float* g_w1     = (const float*)d_in[17];
  const float* g_b1     = (const float*)d_in[18];
  const float* g_w2     = (const float*)d_in[19];
  const float* g_b2     = (const float*)d_in[20];
  float* ws  = (float*)d_ws;
  float* out = (float*)d_out;
  unsigned short* BUFA = (unsigned short*)(ws + OFF_BUFA);
  unsigned short* BUFB = (unsigned short*)(ws + OFF_BUFB);
  const unsigned short* aqh = (const unsigned short*)(ws + OFF_AQH);
  const unsigned short* aql = (const unsigned short*)(ws + OFF_AQL);
  const unsigned short* afh = (const unsigned short*)(ws + OFF_AFH);
  const unsigned short* afl = (const unsigned short*)(ws + OFF_AFL);
  const unsigned short* aoh = (const unsigned short*)(ws + OFF_AOH);
  const unsigned short* aol = (const unsigned short*)(ws + OFF_AOL);

  k_init<<<dim3(8), dim3(256), 0, stream>>>(ws);
  k_prep<<<dim3(451), dim3(256), 0, stream>>>(wq_pw, wk_pw, wv_pw, f1_pw, f2_pw, f_out,
                                              ln_in_w, ln_in_b, ln_out_w, ln_out_b, ws);
  k_stats<<<dim3(36,4), dim3(256), 0, stream>>>(x, ws);
  // QKV 1x1 (LN folded, MFMA): x -> BUFA [q1|k1|v1] bf16
  k_gemm_mfma<false,false><<<dim3(3,288,4), dim3(512), 0, stream>>>(
      x, 128, aqh, aql, ws+OFF_RS_QKV, ws+OFF_B_QKV,
      ws+OFF_MU1, ws+OFF_RSTD1, BUFA, 0);
  // dw: q2 -> BUFB ch0 (+ssq0), k2 -> BUFB ch128 (+ssq128), v2 -> BUFB ch256
  k_dw<false,true><<<dim3(24,128,4), dim3(256), 0, stream>>>(
      BUFA, wq_dw, BUFB, ws+OFF_SSQ, 0);
  k_dw<false,true><<<dim3(24,128,4), dim3(256), 0, stream>>>(
      BUFA + (size_t)128*HW, wk_dw, BUFB + (size_t)128*HW, ws+OFF_SSQ, 128);
  k_dw<false,false><<<dim3(24,128,4), dim3(256), 0, stream>>>(
      BUFA + (size_t)256*HW, wv_dw, BUFB + (size_t)256*HW, nullptr, 0);
  // gram partials + softmax
  k_qk<<<dim3(64,2,4), dim3(256), 0, stream>>>(BUFB, ws+OFF_PART);
  k_softmax<<<dim3(8,2,4), dim3(256), 0, stream>>>(
      ws+OFF_PART, ws+OFF_SSQ, scale, ws+OFF_A, out);
  // out = a @ v2 -> BUFA ch0 (bf16) + LN2 stats
  k_av<<<dim3(576,4), dim3(256), 0, stream>>>(
      ws+OFF_A, BUFB, BUFA, ws+OFF_MU2, ws+OFF_RSTD2);
  // FFN 1x1 (LN folded, MFMA) + GELU: BUFA ch0 -> BUFA ch128..383 [g1|g2]
  k_gemm_mfma<true,true><<<dim3(2,288,4), dim3(512), 0, stream>>>(
      BUFA, 384, afh, afl, ws+OFF_RS_FFN, ws+OFF_B_FFN,
      ws+OFF_MU2, ws+OFF_RSTD2, BUFA, 128);
  // z1 = gelu(dw(g1)) -> BUFB ch0; z2 = gelu(dw(g2)) -> BUFB ch128
  k_dw<true,false><<<dim3(24,128,4), dim3(256), 0, stream>>>(
      BUFA + (size_t)128*HW, f1_dw, BUFB, nullptr, 0);
  k_dw<true,false><<<dim3(24,128,4), dim3(256), 0, stream>>>(
      BUFA + (size_t)256*HW, f2_dw, BUFB + (size_t)128*HW, nullptr, 0);
  // f_out GEMM (MFMA) + pools
  k_fout_mfma<<<dim3(288,4), dim3(512), 0, stream>>>(
      BUFB, aoh, aol, ws+OFF_AVG, (unsigned*)(ws+OFF_MAXK));
  k_gate<<<dim3(4), dim3(128), 0, stream>>>(
      ws+OFF_AVG, (const unsigned*)(ws+OFF_MAXK), g_w1, g_b1, g_w2, g_b2, out);

  (void)in_sizes; (void)n_in; (void)out_size; (void)ws_size;
}